// Round 1
// baseline (443.618 us; speedup 1.0000x reference)
//
#include <hip/hip_runtime.h>

// Controlled 2-qubit gate on a 26-qubit float32 state vector.
// Flat index bits: q0 = bit 25, q1 = bit 24, control q2 = bit 23, r = bits 0..22.
// For q2 == 1: out[t] = sum_s M[t][s] * a[s] over the 4 target combos
//   t = 2*q0 + q1 -> offsets {0, 1<<24, 1<<25, (1<<24)|(1<<25)}.
// For q2 == 0: copy.

constexpr unsigned kOff1 = 1u << 24;   // q1 bit
constexpr unsigned kOff2 = 1u << 25;   // q0 bit
constexpr unsigned kCtrl = 1u << 23;   // q2 bit

__global__ __launch_bounds__(256) void gate_kernel(const float* __restrict__ x,
                                                   const float* __restrict__ mat,
                                                   float* __restrict__ out) {
    const unsigned tid = blockIdx.x * blockDim.x + threadIdx.x;   // [0, 2^22)
    const unsigned e = tid << 2;                                  // element index in [0, 2^24), %4==0

    const float4* __restrict__ x4 = (const float4*)x;
    float4* __restrict__ o4 = (float4*)out;

    const unsigned i0 = e >> 2;
    const unsigned i1 = (e + kOff1) >> 2;
    const unsigned i2 = (e + kOff2) >> 2;
    const unsigned i3 = (e + kOff1 + kOff2) >> 2;

    float4 a0 = x4[i0];
    float4 a1 = x4[i1];
    float4 a2 = x4[i2];
    float4 a3 = x4[i3];

    if (e & kCtrl) {   // wave-uniform branch (bit 21 of tid)
        float m[16];
#pragma unroll
        for (int k = 0; k < 16; ++k) m[k] = mat[k];

        float4 b0, b1, b2, b3;
        b0.x = m[0]*a0.x + m[1]*a1.x + m[2]*a2.x + m[3]*a3.x;
        b0.y = m[0]*a0.y + m[1]*a1.y + m[2]*a2.y + m[3]*a3.y;
        b0.z = m[0]*a0.z + m[1]*a1.z + m[2]*a2.z + m[3]*a3.z;
        b0.w = m[0]*a0.w + m[1]*a1.w + m[2]*a2.w + m[3]*a3.w;

        b1.x = m[4]*a0.x + m[5]*a1.x + m[6]*a2.x + m[7]*a3.x;
        b1.y = m[4]*a0.y + m[5]*a1.y + m[6]*a2.y + m[7]*a3.y;
        b1.z = m[4]*a0.z + m[5]*a1.z + m[6]*a2.z + m[7]*a3.z;
        b1.w = m[4]*a0.w + m[5]*a1.w + m[6]*a2.w + m[7]*a3.w;

        b2.x = m[8]*a0.x + m[9]*a1.x + m[10]*a2.x + m[11]*a3.x;
        b2.y = m[8]*a0.y + m[9]*a1.y + m[10]*a2.y + m[11]*a3.y;
        b2.z = m[8]*a0.z + m[9]*a1.z + m[10]*a2.z + m[11]*a3.z;
        b2.w = m[8]*a0.w + m[9]*a1.w + m[10]*a2.w + m[11]*a3.w;

        b3.x = m[12]*a0.x + m[13]*a1.x + m[14]*a2.x + m[15]*a3.x;
        b3.y = m[12]*a0.y + m[13]*a1.y + m[14]*a2.y + m[15]*a3.y;
        b3.z = m[12]*a0.z + m[13]*a1.z + m[14]*a2.z + m[15]*a3.z;
        b3.w = m[12]*a0.w + m[13]*a1.w + m[14]*a2.w + m[15]*a3.w;

        a0 = b0; a1 = b1; a2 = b2; a3 = b3;
    }

    o4[i0] = a0;
    o4[i1] = a1;
    o4[i2] = a2;
    o4[i3] = a3;
}

extern "C" void kernel_launch(void* const* d_in, const int* in_sizes, int n_in,
                              void* d_out, int out_size, void* d_ws, size_t ws_size,
                              hipStream_t stream) {
    const float* x   = (const float*)d_in[0];   // 2^26 floats
    const float* mat = (const float*)d_in[1];   // 16 floats, row-major 4x4
    float* out = (float*)d_out;                 // 2^26 floats

    const unsigned n_threads = 1u << 22;        // (2^24 elements in (q2,r) space) / 4 per thread
    const unsigned block = 256;
    const unsigned grid = n_threads / block;    // 16384
    gate_kernel<<<grid, block, 0, stream>>>(x, mat, out);
}